// Round 15
// baseline (149.740 us; speedup 1.0000x reference)
//
#include <hip/hip_runtime.h>
#include <hip/hip_bf16.h>

#define B_SZ 2
#define H_SZ 16
#define S_SZ 2048
#define D_SZ 64
#define WAVES 8
#define NBH  (B_SZ * H_SZ)      // 32
#define NQB  (S_SZ / 16)        // 128 16-row blocks
#define NUB  (S_SZ / 32)        // 64 32-row V blocks

typedef _Float16 half8 __attribute__((ext_vector_type(8)));
typedef _Float16 half4 __attribute__((ext_vector_type(4)));
typedef float    f32x4 __attribute__((ext_vector_type(4)));

// d_ws layout: pre-swizzled fp16 MFMA fragments (8 MB segments)
#define SEG   (8u * 1024u * 1024u)
#define QF_OFF  (0 * (size_t)SEG)
#define KF_OFF  (1 * (size_t)SEG)
#define VSW_OFF (2 * (size_t)SEG)

// ---- fused prep: blocks [0,2048) convert Q/K to fp16 fragments;
// blocks [2048,2560) build pi-permuted V fragments via LDS transpose.
__global__ __launch_bounds__(256) void prep_qkv(
    const float* __restrict__ Q, const float* __restrict__ K,
    const float* __restrict__ V, char* __restrict__ ws)
{
    __shared__ float vt[4][32 * 68];
    const int lane = threadIdx.x & 63;
    const int wv   = threadIdx.x >> 6;
    const int l15  = lane & 15;
    const int g    = lane >> 4;

    if (blockIdx.x < 2048) {
        const int wid  = blockIdx.x * 4 + wv;      // 0..8191
        const int tensor = wid >> 12;
        const int rem  = wid & 4095;
        const int bh   = rem >> 7;
        const int blk  = rem & 127;

        const float* src = (tensor ? K : Q) + ((size_t)bh * S_SZ + blk * 16 + l15) * D_SZ;
        half8* dst = (half8*)(ws + (tensor ? KF_OFF : QF_OFF));

        #pragma unroll
        for (int ks = 0; ks < 2; ++ks) {
            const float* p = src + 32 * ks + 8 * g;
            f32x4 a = *(const f32x4*)p;
            f32x4 b = *(const f32x4*)(p + 4);
            half8 v;
            #pragma unroll
            for (int j = 0; j < 4; ++j) {
                v[j]     = (_Float16)a[j];
                v[4 + j] = (_Float16)b[j];
            }
            dst[((size_t)(bh * NQB + blk) * 2 + ks) * 64 + lane] = v;
        }
    } else {
        const int wid = (blockIdx.x - 2048) * 4 + wv;   // 0..2047
        const int bh  = wid >> 6;
        const int u   = wid & 63;

        const float* src = V + ((size_t)bh * S_SZ + u * 32) * D_SZ;
        float* t = vt[wv];
        #pragma unroll
        for (int i = 0; i < 8; ++i) {
            int idx = i * 64 + lane;
            int row = idx >> 4;
            int c4  = idx & 15;
            *(f32x4*)(t + row * 68 + c4 * 4) = *(const f32x4*)(src + row * 64 + c4 * 4);
        }
        __syncthreads();

        half8* vsw = (half8*)(ws + VSW_OFF);
        #pragma unroll
        for (int db = 0; db < 4; ++db) {
            half8 vb;
            #pragma unroll
            for (int j = 0; j < 8; ++j) {
                int kk = (j < 4) ? (4 * g + j) : (16 + 4 * g + (j - 4));
                vb[j] = (_Float16)t[kk * 68 + 16 * db + l15];
            }
            vsw[((size_t)(bh * NUB + u) * 4 + db) * 64 + lane] = vb;
        }
    }
}

// ---- main fused kernel (R14 skeleton; sweep INTERLEAVED into PV).
// Per PV iteration u: 2 sweep sub-chunks {LDS read + NT store} followed by
// 4 {V load + MFMA} -- every wave keeps the HBM-write pipe and the L2-read
// pipe fed simultaneously; no coarse phase separation remains.
__global__ __launch_bounds__(512, 4) void attn_fused12(
    const char* __restrict__ ws, float* __restrict__ OutC, float* __restrict__ OutW)
{
    __shared__ __align__(16) char smem[66560];   // 64KB W-tile + redm + reds
    float* redm = (float*)(smem + 65536);        // [8][16]
    float* reds = (float*)(smem + 65536 + 512);  // [8][16]

    const int tid  = threadIdx.x;
    const int lane = tid & 63;
    const int wv   = tid >> 6;
    const int l15  = lane & 15;
    const int g    = lane >> 4;

    // XCD-aware swizzle: XCD x owns bh range [4x, 4x+4)
    const int b    = blockIdx.x;
    const int work = (b & 7) * 512 + (b >> 3);
    const int bh   = work >> 7;
    const int qt   = work & 127;
    const int q0   = qt * 16;

    const half8* QF  = (const half8*)(ws + QF_OFF);
    const half8* KF  = (const half8*)(ws + KF_OFF);
    const half8* VSW = (const half8*)(ws + VSW_OFF);

    float* Wb = OutW + (size_t)bh * S_SZ * S_SZ;
    float* Cb = OutC + (size_t)bh * S_SZ * D_SZ;

    // Q fragments
    half8 qf[2];
    {
        size_t qi = ((size_t)(bh * NQB + qt) * 2) * 64 + lane;
        qf[0] = QF[qi];       qf[1] = QF[qi + 64];
    }

    // QK^T: 16 col-blocks per wave, 2 fp16 MFMA each
    f32x4 s[16];
    const int kb0 = wv * 16;
    #pragma unroll
    for (int cb = 0; cb < 16; ++cb) {
        size_t bi = ((size_t)(bh * NQB + kb0 + cb) * 2) * 64 + lane;
        half8 kf0 = KF[bi], kf1 = KF[bi + 64];
        f32x4 acc = {0.f, 0.f, 0.f, 0.f};
        acc = __builtin_amdgcn_mfma_f32_16x16x32_f16(kf0, qf[0], acc, 0, 0, 0);
        acc = __builtin_amdgcn_mfma_f32_16x16x32_f16(kf1, qf[1], acc, 0, 0, 0);
        s[cb] = acc;
    }

    // row max
    float m = -3.0e38f;
    #pragma unroll
    for (int cb = 0; cb < 16; ++cb) {
        #pragma unroll
        for (int r = 0; r < 4; ++r) m = fmaxf(m, s[cb][r]);
    }
    m = fmaxf(m, __shfl_xor(m, 16));
    m = fmaxf(m, __shfl_xor(m, 32));
    if (lane < 16) redm[wv * 16 + l15] = m;
    __syncthreads();
    float mall = redm[l15];
    #pragma unroll
    for (int w2 = 1; w2 < WAVES; ++w2) mall = fmaxf(mall, redm[w2 * 16 + l15]);

    // exp + row sum
    float sm = 0.f;
    #pragma unroll
    for (int cb = 0; cb < 16; ++cb) {
        #pragma unroll
        for (int r = 0; r < 4; ++r) {
            float e = __expf(s[cb][r] - mall);
            s[cb][r] = e;
            sm += e;
        }
    }
    sm += __shfl_xor(sm, 16);
    sm += __shfl_xor(sm, 32);
    if (lane < 16) reds[wv * 16 + l15] = sm;
    __syncthreads();
    float lsum = 0.f;
    #pragma unroll
    for (int w2 = 0; w2 < WAVES; ++w2) lsum += reds[w2 * 16 + l15];
    const float inv = 1.0f / lsum;

    // normalize -> pack P to fp16 -> stage W tile in LDS (frees s[])
    half8 pa[8];
    const int swz = (l15 & 7) << 4;
    #pragma unroll
    for (int u = 0; u < 8; ++u) {
        f32x4 w0, w1;
        #pragma unroll
        for (int r = 0; r < 4; ++r) {
            w0[r] = s[2 * u][r]     * inv;
            w1[r] = s[2 * u + 1][r] * inv;
        }
        #pragma unroll
        for (int r = 0; r < 4; ++r) {
            pa[u][r]     = (_Float16)w0[r];
            pa[u][4 + r] = (_Float16)w1[r];
        }
        const uint2* pau = (const uint2*)&pa[u];
        int c4a = wv * 64 + (2 * u) * 4 + g;
        int c4b = c4a + 4;
        *(uint2*)(smem + l15 * 4096 + ((c4a * 8) ^ swz)) = pau[0];
        *(uint2*)(smem + l15 * 4096 + ((c4b * 8) ^ swz)) = pau[1];
    }
    __syncthreads();

    // PV with interleaved sweep: per iteration, 2x{LDS read + NT store W}
    // then 4x{V load + MFMA}. Store issue is spread across the whole PV
    // duration -> HBM-write pipe and L2-read pipe run concurrently.
    f32x4 ctx[4];
    #pragma unroll
    for (int db = 0; db < 4; ++db) ctx[db] = (f32x4){0.f, 0.f, 0.f, 0.f};

    float* Wrow = Wb + (size_t)q0 * S_SZ;
    #pragma unroll
    for (int u = 0; u < 8; ++u) {
        #pragma unroll
        for (int h = 0; h < 2; ++h) {
            int unit = (2 * u + h) * 512 + tid;    // 8B units; 512 units/row
            int row  = unit >> 9;
            int c4   = unit & 511;
            half4 hv = *(const half4*)(smem + row * 4096 + ((c4 * 8) ^ ((row & 7) << 4)));
            f32x4 f;
            #pragma unroll
            for (int j = 0; j < 4; ++j) f[j] = (float)hv[j];
            __builtin_nontemporal_store(f, (f32x4*)(Wrow + (size_t)row * S_SZ + c4 * 4));
        }
        size_t vbase = ((size_t)(bh * NUB + wv * 8 + u) * 4) * 64 + lane;
        #pragma unroll
        for (int db = 0; db < 4; ++db) {
            half8 vb = VSW[vbase + (size_t)db * 64];
            ctx[db] = __builtin_amdgcn_mfma_f32_16x16x32_f16(pa[u], vb, ctx[db], 0, 0, 0);
        }
    }

    // ctxred reusing W-LDS
    __syncthreads();
    float* ctxred = (float*)smem;    // [8][16][64]
    #pragma unroll
    for (int db = 0; db < 4; ++db) {
        #pragma unroll
        for (int r = 0; r < 4; ++r)
            ctxred[(wv * 16 + 4 * g + r) * 64 + 16 * db + l15] = ctx[db][r];
    }
    __syncthreads();
    {
        const int qr = tid >> 6;
        const int d  = tid & 63;
        float acc0 = 0.f, acc1 = 0.f;
        #pragma unroll
        for (int w2 = 0; w2 < WAVES; ++w2) {
            acc0 += ctxred[(w2 * 16 + qr) * 64 + d];
            acc1 += ctxred[(w2 * 16 + qr + 8) * 64 + d];
        }
        __builtin_nontemporal_store(acc0, Cb + (size_t)(q0 + qr) * D_SZ + d);
        __builtin_nontemporal_store(acc1, Cb + (size_t)(q0 + qr + 8) * D_SZ + d);
    }
}

extern "C" void kernel_launch(void* const* d_in, const int* in_sizes, int n_in,
                              void* d_out, int out_size, void* d_ws, size_t ws_size,
                              hipStream_t stream)
{
    const float* Q = (const float*)d_in[0];
    const float* K = (const float*)d_in[1];
    const float* V = (const float*)d_in[2];
    float* ctx = (float*)d_out;
    float* w   = (float*)d_out + (size_t)B_SZ * H_SZ * S_SZ * D_SZ;
    char*  ws  = (char*)d_ws;

    prep_qkv<<<2560, 256, 0, stream>>>(Q, K, V, ws);
    attn_fused12<<<4096, 512, 0, stream>>>(ws, ctx, w);
}

// Round 16
// 144.026 us; speedup vs baseline: 1.0397x; 1.0397x over previous
//
#include <hip/hip_runtime.h>
#include <hip/hip_bf16.h>

#define B_SZ 2
#define H_SZ 16
#define S_SZ 2048
#define D_SZ 64
#define WAVES 8
#define NBH  (B_SZ * H_SZ)      // 32
#define NQB  (S_SZ / 16)        // 128 16-row blocks
#define NUB  (S_SZ / 32)        // 64 32-row V blocks

typedef _Float16 half8 __attribute__((ext_vector_type(8)));
typedef _Float16 half4 __attribute__((ext_vector_type(4)));
typedef float    f32x4 __attribute__((ext_vector_type(4)));

// d_ws layout: pre-swizzled fp16 MFMA fragments (8 MB segments)
#define SEG   (8u * 1024u * 1024u)
#define QF_OFF  (0 * (size_t)SEG)
#define KF_OFF  (1 * (size_t)SEG)
#define VSW_OFF (2 * (size_t)SEG)

// ---- fused prep, XCD-aligned with consumers: block b runs on XCD (b&7)
// and preps bh-group [4*(b&7), 4*(b&7)+4) -- the same group the main
// kernel's swizzle assigns to that XCD, so fragments stay in its L2.
// Blocks [0,2048): Q/K fp16 fragments. Blocks [2048,2560): pi-permuted V.
__global__ __launch_bounds__(256) void prep_qkv(
    const float* __restrict__ Q, const float* __restrict__ K,
    const float* __restrict__ V, char* __restrict__ ws)
{
    __shared__ float vt[4][32 * 68];
    const int lane = threadIdx.x & 63;
    const int wv   = threadIdx.x >> 6;
    const int l15  = lane & 15;
    const int g    = lane >> 4;
    const int bx   = blockIdx.x;
    const int xcd  = bx & 7;

    if (bx < 2048) {
        const int idx = bx >> 3;            // 0..255
        const int wt  = idx * 4 + wv;       // 0..1023 per xcd
        const int tensor = wt >> 9;         // 0=Q, 1=K
        const int bh  = xcd * 4 + ((wt >> 7) & 3);
        const int blk = wt & 127;

        const float* src = (tensor ? K : Q) + ((size_t)bh * S_SZ + blk * 16 + l15) * D_SZ;
        half8* dst = (half8*)(ws + (tensor ? KF_OFF : QF_OFF));

        #pragma unroll
        for (int ks = 0; ks < 2; ++ks) {
            const float* p = src + 32 * ks + 8 * g;
            f32x4 a = *(const f32x4*)p;
            f32x4 b = *(const f32x4*)(p + 4);
            half8 v;
            #pragma unroll
            for (int j = 0; j < 4; ++j) {
                v[j]     = (_Float16)a[j];
                v[4 + j] = (_Float16)b[j];
            }
            dst[((size_t)(bh * NQB + blk) * 2 + ks) * 64 + lane] = v;
        }
    } else {
        const int idx = (bx - 2048) >> 3;   // 0..63
        const int wt  = idx * 4 + wv;       // 0..255 per xcd
        const int bh  = xcd * 4 + (wt >> 6);
        const int u   = wt & 63;

        const float* src = V + ((size_t)bh * S_SZ + u * 32) * D_SZ;
        float* t = vt[wv];
        #pragma unroll
        for (int i = 0; i < 8; ++i) {
            int idx2 = i * 64 + lane;
            int row  = idx2 >> 4;
            int c4   = idx2 & 15;
            *(f32x4*)(t + row * 68 + c4 * 4) = *(const f32x4*)(src + row * 64 + c4 * 4);
        }
        __syncthreads();

        half8* vsw = (half8*)(ws + VSW_OFF);
        #pragma unroll
        for (int db = 0; db < 4; ++db) {
            half8 vb;
            #pragma unroll
            for (int j = 0; j < 8; ++j) {
                int kk = (j < 4) ? (4 * g + j) : (16 + 4 * g + (j - 4));
                vb[j] = (_Float16)t[kk * 68 + 16 * db + l15];
            }
            vsw[((size_t)(bh * NUB + u) * 4 + db) * 64 + lane] = vb;
        }
    }
}

// ---- main fused kernel (R14-exact: best known, 144 us).
// Parity-alternated PV/sweep: even wgs PV->sweep, odd wgs sweep->PV, so
// co-resident wgs sit in opposite phases (HBM-write pipe || L2-read pipe).
__global__ __launch_bounds__(512, 4) void attn_fused11(
    const char* __restrict__ ws, float* __restrict__ OutC, float* __restrict__ OutW)
{
    __shared__ __align__(16) char smem[66560];   // 64KB W-tile + redm + reds
    float* redm = (float*)(smem + 65536);        // [8][16]
    float* reds = (float*)(smem + 65536 + 512);  // [8][16]

    const int tid  = threadIdx.x;
    const int lane = tid & 63;
    const int wv   = tid >> 6;
    const int l15  = lane & 15;
    const int g    = lane >> 4;

    // XCD-aware swizzle: XCD x owns bh range [4x, 4x+4)
    const int b    = blockIdx.x;
    const int work = (b & 7) * 512 + (b >> 3);
    const int bh   = work >> 7;
    const int qt   = work & 127;
    const int q0   = qt * 16;

    const half8* QF  = (const half8*)(ws + QF_OFF);
    const half8* KF  = (const half8*)(ws + KF_OFF);
    const half8* VSW = (const half8*)(ws + VSW_OFF);

    float* Wb = OutW + (size_t)bh * S_SZ * S_SZ;
    float* Cb = OutC + (size_t)bh * S_SZ * D_SZ;

    // Q fragments
    half8 qf[2];
    {
        size_t qi = ((size_t)(bh * NQB + qt) * 2) * 64 + lane;
        qf[0] = QF[qi];       qf[1] = QF[qi + 64];
    }

    // QK^T: 16 col-blocks per wave, 2 fp16 MFMA each
    f32x4 s[16];
    const int kb0 = wv * 16;
    #pragma unroll
    for (int cb = 0; cb < 16; ++cb) {
        size_t bi = ((size_t)(bh * NQB + kb0 + cb) * 2) * 64 + lane;
        half8 kf0 = KF[bi], kf1 = KF[bi + 64];
        f32x4 acc = {0.f, 0.f, 0.f, 0.f};
        acc = __builtin_amdgcn_mfma_f32_16x16x32_f16(kf0, qf[0], acc, 0, 0, 0);
        acc = __builtin_amdgcn_mfma_f32_16x16x32_f16(kf1, qf[1], acc, 0, 0, 0);
        s[cb] = acc;
    }

    // row max
    float m = -3.0e38f;
    #pragma unroll
    for (int cb = 0; cb < 16; ++cb) {
        #pragma unroll
        for (int r = 0; r < 4; ++r) m = fmaxf(m, s[cb][r]);
    }
    m = fmaxf(m, __shfl_xor(m, 16));
    m = fmaxf(m, __shfl_xor(m, 32));
    if (lane < 16) redm[wv * 16 + l15] = m;
    __syncthreads();
    float mall = redm[l15];
    #pragma unroll
    for (int w2 = 1; w2 < WAVES; ++w2) mall = fmaxf(mall, redm[w2 * 16 + l15]);

    // exp + row sum
    float sm = 0.f;
    #pragma unroll
    for (int cb = 0; cb < 16; ++cb) {
        #pragma unroll
        for (int r = 0; r < 4; ++r) {
            float e = __expf(s[cb][r] - mall);
            s[cb][r] = e;
            sm += e;
        }
    }
    sm += __shfl_xor(sm, 16);
    sm += __shfl_xor(sm, 32);
    if (lane < 16) reds[wv * 16 + l15] = sm;
    __syncthreads();
    float lsum = 0.f;
    #pragma unroll
    for (int w2 = 0; w2 < WAVES; ++w2) lsum += reds[w2 * 16 + l15];
    const float inv = 1.0f / lsum;

    // normalize -> pack P to fp16 -> stage W tile in LDS (frees s[])
    half8 pa[8];
    const int swz = (l15 & 7) << 4;
    #pragma unroll
    for (int u = 0; u < 8; ++u) {
        f32x4 w0, w1;
        #pragma unroll
        for (int r = 0; r < 4; ++r) {
            w0[r] = s[2 * u][r]     * inv;
            w1[r] = s[2 * u + 1][r] * inv;
        }
        #pragma unroll
        for (int r = 0; r < 4; ++r) {
            pa[u][r]     = (_Float16)w0[r];
            pa[u][4 + r] = (_Float16)w1[r];
        }
        const uint2* pau = (const uint2*)&pa[u];
        int c4a = wv * 64 + (2 * u) * 4 + g;
        int c4b = c4a + 4;
        *(uint2*)(smem + l15 * 4096 + ((c4a * 8) ^ swz)) = pau[0];
        *(uint2*)(smem + l15 * 4096 + ((c4b * 8) ^ swz)) = pau[1];
    }
    __syncthreads();

    f32x4 ctx[4];
    #pragma unroll
    for (int db = 0; db < 4; ++db) ctx[db] = (f32x4){0.f, 0.f, 0.f, 0.f};

    const bool pvFirst = (work & 1) == 0;

    if (pvFirst) {
        // PV then sweep
        #pragma unroll
        for (int u = 0; u < 8; ++u) {
            size_t vbase = ((size_t)(bh * NUB + wv * 8 + u) * 4) * 64 + lane;
            #pragma unroll
            for (int db = 0; db < 4; ++db) {
                half8 vb = VSW[vbase + (size_t)db * 64];
                ctx[db] = __builtin_amdgcn_mfma_f32_16x16x32_f16(pa[u], vb, ctx[db], 0, 0, 0);
            }
        }
        float* Wrow = Wb + (size_t)q0 * S_SZ;
        #pragma unroll
        for (int sidx = 0; sidx < 16; ++sidx) {
            int unit = sidx * 512 + tid;
            int row  = unit >> 9;
            int c4   = unit & 511;
            half4 hv = *(const half4*)(smem + row * 4096 + ((c4 * 8) ^ ((row & 7) << 4)));
            f32x4 f;
            #pragma unroll
            for (int j = 0; j < 4; ++j) f[j] = (float)hv[j];
            __builtin_nontemporal_store(f, (f32x4*)(Wrow + (size_t)row * S_SZ + c4 * 4));
        }
    } else {
        // sweep then PV
        float* Wrow = Wb + (size_t)q0 * S_SZ;
        #pragma unroll
        for (int sidx = 0; sidx < 16; ++sidx) {
            int unit = sidx * 512 + tid;
            int row  = unit >> 9;
            int c4   = unit & 511;
            half4 hv = *(const half4*)(smem + row * 4096 + ((c4 * 8) ^ ((row & 7) << 4)));
            f32x4 f;
            #pragma unroll
            for (int j = 0; j < 4; ++j) f[j] = (float)hv[j];
            __builtin_nontemporal_store(f, (f32x4*)(Wrow + (size_t)row * S_SZ + c4 * 4));
        }
        #pragma unroll
        for (int u = 0; u < 8; ++u) {
            size_t vbase = ((size_t)(bh * NUB + wv * 8 + u) * 4) * 64 + lane;
            #pragma unroll
            for (int db = 0; db < 4; ++db) {
                half8 vb = VSW[vbase + (size_t)db * 64];
                ctx[db] = __builtin_amdgcn_mfma_f32_16x16x32_f16(pa[u], vb, ctx[db], 0, 0, 0);
            }
        }
    }

    // ctxred reusing W-LDS
    __syncthreads();
    float* ctxred = (float*)smem;    // [8][16][64]
    #pragma unroll
    for (int db = 0; db < 4; ++db) {
        #pragma unroll
        for (int r = 0; r < 4; ++r)
            ctxred[(wv * 16 + 4 * g + r) * 64 + 16 * db + l15] = ctx[db][r];
    }
    __syncthreads();
    {
        const int qr = tid >> 6;
        const int d  = tid & 63;
        float acc0 = 0.f, acc1 = 0.f;
        #pragma unroll
        for (int w2 = 0; w2 < WAVES; ++w2) {
            acc0 += ctxred[(w2 * 16 + qr) * 64 + d];
            acc1 += ctxred[(w2 * 16 + qr + 8) * 64 + d];
        }
        __builtin_nontemporal_store(acc0, Cb + (size_t)(q0 + qr) * D_SZ + d);
        __builtin_nontemporal_store(acc1, Cb + (size_t)(q0 + qr + 8) * D_SZ + d);
    }
}

extern "C" void kernel_launch(void* const* d_in, const int* in_sizes, int n_in,
                              void* d_out, int out_size, void* d_ws, size_t ws_size,
                              hipStream_t stream)
{
    const float* Q = (const float*)d_in[0];
    const float* K = (const float*)d_in[1];
    const float* V = (const float*)d_in[2];
    float* ctx = (float*)d_out;
    float* w   = (float*)d_out + (size_t)B_SZ * H_SZ * S_SZ * D_SZ;
    char*  ws  = (char*)d_ws;

    prep_qkv<<<2560, 256, 0, stream>>>(Q, K, V, ws);
    attn_fused11<<<4096, 512, 0, stream>>>(ws, ctx, w);
}